// Round 2
// baseline (4727.444 us; speedup 1.0000x reference)
//
#include <hip/hip_runtime.h>

// DGCNN inference, MI355X gfx950. B=8, N=4096, K=20. fp32 in/out, fp32 internal.

constexpr int NB  = 8;
constexpr int NPT = 4096;
constexpr int KNB = 20;

// ---- convert xyz fp32 [B][N][3] -> fp32 [B][N][4] (pad 0) ----
__global__ __launch_bounds__(256) void cvt_xyz(const float* __restrict__ xyz,
                                               float* __restrict__ x0) {
  const int t = blockIdx.x * 256 + threadIdx.x;  // < B*N
  float4 v;
  v.x = xyz[t * 3 + 0];
  v.y = xyz[t * 3 + 1];
  v.z = xyz[t * 3 + 2];
  v.w = 0.0f;
  *(float4*)(x0 + (size_t)t * 4) = v;
}

// ---- squared norms ----
template <int D, int DS>
__global__ __launch_bounds__(256) void sq_kernel(const float* __restrict__ x,
                                                 float* __restrict__ sqo) {
  const int t = blockIdx.x * 256 + threadIdx.x;  // < B*N
  const float* p = x + (size_t)t * DS;
  float s;
  if constexpr (D == 3) {
    const float4 v = *(const float4*)p;
    s = v.x * v.x + v.y * v.y + v.z * v.z;
  } else {
    s = 0.0f;
#pragma unroll
    for (int d = 0; d < D; d += 4) {
      const float4 v = *(const float4*)(p + d);
      s += v.x * v.x + v.y * v.y + v.z * v.z + v.w * v.w;
    }
  }
  sqo[t] = s;
}

// ---- fused distance-GEMM + top-20 selection ----
// grid (N/64, B), block 256. Block owns 64 i-points; 4 waves x 16 i-slots.
// Lists: sorted ascending, entry m of slot s lives in lane m (m<20), reg slot s.
template <int D, int DS>
__global__ __launch_bounds__(256) void knn_kernel(const float* __restrict__ x,
                                                  const float* __restrict__ sqn,
                                                  int* __restrict__ idxout) {
  const int b = blockIdx.y;
  const int i0 = blockIdx.x * 64;
  __shared__ float xi_t[D][64];   // k-major tiles
  __shared__ float xj_t[D][64];
  __shared__ float dist_t[64][64];
  __shared__ float sqi_s[64];
  __shared__ float sqj_s[64];
  const int tid = threadIdx.x;
  const float* xb = x + (size_t)b * (NPT * DS);
  const float* sqb = sqn + b * NPT;

  if constexpr (D == 3) {
    if (tid < 64) {
      const float4 v = *(const float4*)(xb + (size_t)(i0 + tid) * DS);
      xi_t[0][tid] = v.x; xi_t[1][tid] = v.y; xi_t[2][tid] = v.z;
      sqi_s[tid] = sqb[i0 + tid];
    }
  } else {
#pragma unroll
    for (int p = 0; p < 4; ++p) {
      const int q = tid + p * 256;      // [0,1024)
      const int r = q >> 4, c4 = q & 15;
      const float4 v = *(const float4*)(xb + (size_t)(i0 + r) * DS + c4 * 4);
      xi_t[c4 * 4 + 0][r] = v.x; xi_t[c4 * 4 + 1][r] = v.y;
      xi_t[c4 * 4 + 2][r] = v.z; xi_t[c4 * 4 + 3][r] = v.w;
    }
    if (tid < 64) sqi_s[tid] = sqb[i0 + tid];
  }

  float lst_d[16];
  int lst_j[16];
#pragma unroll
  for (int s = 0; s < 16; ++s) { lst_d[s] = 3.0e38f; lst_j[s] = 0; }

  const int wav = tid >> 6, lane = tid & 63;
  const int ty = tid >> 4, tx = tid & 15;

  for (int jt = 0; jt < NPT / 64; ++jt) {
    const int j0 = jt * 64;
    if constexpr (D == 3) {
      if (tid < 64) {
        const float4 v = *(const float4*)(xb + (size_t)(j0 + tid) * DS);
        xj_t[0][tid] = v.x; xj_t[1][tid] = v.y; xj_t[2][tid] = v.z;
        sqj_s[tid] = sqb[j0 + tid];
      }
    } else {
#pragma unroll
      for (int p = 0; p < 4; ++p) {
        const int q = tid + p * 256;
        const int r = q >> 4, c4 = q & 15;
        const float4 v = *(const float4*)(xb + (size_t)(j0 + r) * DS + c4 * 4);
        xj_t[c4 * 4 + 0][r] = v.x; xj_t[c4 * 4 + 1][r] = v.y;
        xj_t[c4 * 4 + 2][r] = v.z; xj_t[c4 * 4 + 3][r] = v.w;
      }
      if (tid < 64) sqj_s[tid] = sqb[j0 + tid];
    }
    __syncthreads();  // B1: tiles ready; also fences prev selection vs dist_t

    // 4x4 register-tile GEMM: inner products
    float acc[4][4];
#pragma unroll
    for (int r = 0; r < 4; ++r)
#pragma unroll
      for (int cc = 0; cc < 4; ++cc) acc[r][cc] = 0.0f;
#pragma unroll 8
    for (int k = 0; k < D; ++k) {
      const float4 av = *(const float4*)&xi_t[k][ty * 4];
      const float4 bv = *(const float4*)&xj_t[k][tx * 4];
      const float ar[4] = {av.x, av.y, av.z, av.w};
      const float br[4] = {bv.x, bv.y, bv.z, bv.w};
#pragma unroll
      for (int r = 0; r < 4; ++r)
#pragma unroll
        for (int cc = 0; cc < 4; ++cc) acc[r][cc] = fmaf(ar[r], br[cc], acc[r][cc]);
    }
#pragma unroll
    for (int r = 0; r < 4; ++r) {
      const float si = sqi_s[ty * 4 + r];
      float4 dv;
      dv.x = (si - 2.0f * acc[r][0]) + sqj_s[tx * 4 + 0];
      dv.y = (si - 2.0f * acc[r][1]) + sqj_s[tx * 4 + 1];
      dv.z = (si - 2.0f * acc[r][2]) + sqj_s[tx * 4 + 2];
      dv.w = (si - 2.0f * acc[r][3]) + sqj_s[tx * 4 + 3];
      *(float4*)&dist_t[ty * 4 + r][tx * 4] = dv;
    }
    __syncthreads();  // B2: dist tile ready

    // wave-cooperative top-20 update; wave handles rows wav*16 + s
#pragma unroll
    for (int s = 0; s < 16; ++s) {
      const float d = dist_t[wav * 16 + s][lane];
      unsigned long long cm = __ballot(d < __shfl(lst_d[s], 19, 64));
      while (cm) {
        const int bit = __builtin_ctzll(cm);
        cm &= cm - 1;
        const float nd = __shfl(d, bit, 64);
        const int nj = j0 + bit;
        const float cur = __shfl(lst_d[s], 19, 64);
        if (nd < cur) {  // uniform across wave
          const bool gt = (lane < 20) && (lst_d[s] > nd);
          const unsigned long long gm = __ballot(gt);
          const int pos = __builtin_ctzll(gm);  // gm != 0 since lane19 qualifies
          const float sd = __shfl_up(lst_d[s], 1, 64);
          const int sj = __shfl_up(lst_j[s], 1, 64);
          if (lane < 20) {
            if (lane > pos)        { lst_d[s] = sd; lst_j[s] = sj; }
            else if (lane == pos)  { lst_d[s] = nd; lst_j[s] = nj; }
          }
        }
      }
    }
  }

#pragma unroll
  for (int s = 0; s < 16; ++s) {
    const int i = i0 + wav * 16 + s;
    if (lane < 20) idxout[((size_t)(b * NPT + i)) * KNB + lane] = lst_j[s];
  }
}

// ---- EdgeConv: conv1x1 + BN + LeakyReLU + max over k neighbors ----
// one wave per (point, 64-channel group).  W [COUT][2*DIN] fp32.
// h_c = Wa_c.x_j + (Wb_c - Wa_c).x_i ;  v = s_c*h + b_c ; lrelu; max_k
template <int DIN, int DS, int COUT>
__global__ __launch_bounds__(256) void edge_kernel(
    const float* __restrict__ x, const int* __restrict__ idx,
    const float* __restrict__ W, const float* __restrict__ g,
    const float* __restrict__ bia, float* __restrict__ out) {
  constexpr int CG = COUT / 64;
  const int lane = threadIdx.x & 63;
  const int wglob = blockIdx.x * 4 + (threadIdx.x >> 6);
  const int n_lin = __builtin_amdgcn_readfirstlane(wglob / CG);  // b*N+n
  const int cg = __builtin_amdgcn_readfirstlane(wglob % CG);
  const int b = n_lin >> 12;
  const int n = n_lin & (NPT - 1);
  const int c = cg * 64 + lane;

  const float* wrow = W + (size_t)c * (2 * DIN);
  const float invs = 1.0f / sqrtf(1.0f + 1e-5f);
  const float s = g[c] * invs;
  const float bias = bia[c];

  const float* xb = x + (size_t)b * (NPT * DS);
  const float* xi = xb + (size_t)n * DS;

  float wa[DIN];
  float base = 0.0f;
  if constexpr (DIN == 3) {
    wa[0] = wrow[0]; wa[1] = wrow[1]; wa[2] = wrow[2];
    const float wb0 = wrow[3], wb1 = wrow[4], wb2 = wrow[5];
    const float4 vi = *(const float4*)xi;
    base = (wb0 - wa[0]) * vi.x + (wb1 - wa[1]) * vi.y + (wb2 - wa[2]) * vi.z;
  } else {
#pragma unroll
    for (int d0 = 0; d0 < DIN; d0 += 4) {
      const float4 w4 = *(const float4*)(wrow + d0);
      wa[d0 + 0] = w4.x; wa[d0 + 1] = w4.y; wa[d0 + 2] = w4.z; wa[d0 + 3] = w4.w;
    }
#pragma unroll
    for (int d0 = 0; d0 < DIN; d0 += 4) {
      const float4 wb4 = *(const float4*)(wrow + DIN + d0);
      const float4 v0 = *(const float4*)(xi + d0);
      base += (wb4.x - wa[d0 + 0]) * v0.x + (wb4.y - wa[d0 + 1]) * v0.y +
              (wb4.z - wa[d0 + 2]) * v0.z + (wb4.w - wa[d0 + 3]) * v0.w;
    }
  }
  base = s * base + bias;

  const int* ip = idx + (size_t)n_lin * KNB;
  float m = -3.0e38f;
  for (int k = 0; k < KNB; ++k) {
    const int j = __builtin_amdgcn_readfirstlane(ip[k]);
    const float* xj = xb + (size_t)j * DS;
    float acc = 0.0f;
    if constexpr (DIN == 3) {
      const float4 v = *(const float4*)xj;
      acc = wa[0] * v.x + wa[1] * v.y + wa[2] * v.z;
    } else {
#pragma unroll
      for (int d0 = 0; d0 < DIN; d0 += 8) {
        const float4 v0 = *(const float4*)(xj + d0);
        const float4 v1 = *(const float4*)(xj + d0 + 4);
        acc += wa[d0 + 0] * v0.x + wa[d0 + 1] * v0.y + wa[d0 + 2] * v0.z +
               wa[d0 + 3] * v0.w + wa[d0 + 4] * v1.x + wa[d0 + 5] * v1.y +
               wa[d0 + 6] * v1.z + wa[d0 + 7] * v1.w;
      }
    }
    float v = s * acc + base;
    v = v > 0.0f ? v : 0.2f * v;
    m = fmaxf(m, v);
  }
  out[(size_t)n_lin * COUT + c] = m;
}

// ---- conv5 (320->1024) + BN + lrelu, fused partial max/sum pooling ----
// grid (128 nb, 4 cb, 8 b); block 256 = 64 cgroups x 4 ngroups; 4c x 8n per thread.
__global__ __launch_bounds__(256) void conv5_kernel(
    const float* __restrict__ x1, const float* __restrict__ x2,
    const float* __restrict__ x3, const float* __restrict__ x4,
    const float* __restrict__ W5, const float* __restrict__ g5,
    const float* __restrict__ b5, float* __restrict__ pmax,
    float* __restrict__ psum) {
  __shared__ float xcT[320][32];
  __shared__ float wT[8][256];
  const int nb = blockIdx.x, cb = blockIdx.y, b = blockIdx.z;
  const int tid = threadIdx.x;
  const int n0 = nb * 32;

#pragma unroll
  for (int p = 0; p < 10; ++p) {
    const int q = tid + p * 256;  // [0,2560) float4s
    const int nloc = q / 80;
    const int kg = (q % 80) * 4;
    const float* src;
    int koff;
    if (kg < 64)       { src = x1 + ((size_t)(b * NPT + n0 + nloc)) * 64;  koff = kg; }
    else if (kg < 128) { src = x2 + ((size_t)(b * NPT + n0 + nloc)) * 64;  koff = kg - 64; }
    else if (kg < 192) { src = x3 + ((size_t)(b * NPT + n0 + nloc)) * 64;  koff = kg - 128; }
    else               { src = x4 + ((size_t)(b * NPT + n0 + nloc)) * 128; koff = kg - 192; }
    const float4 v = *(const float4*)(src + koff);
    xcT[kg + 0][nloc] = v.x; xcT[kg + 1][nloc] = v.y;
    xcT[kg + 2][nloc] = v.z; xcT[kg + 3][nloc] = v.w;
  }

  const int cg = tid >> 2, ng = tid & 3;
  const int c0 = cg * 4, n0t = ng * 8;
  float acc[4][8];
#pragma unroll
  for (int r = 0; r < 4; ++r)
#pragma unroll
    for (int e = 0; e < 8; ++e) acc[r][e] = 0.0f;

  for (int kt = 0; kt < 40; ++kt) {
    __syncthreads();
    {
      const float* wsrc = W5 + (size_t)(cb * 256 + tid) * 320 + kt * 8;
      const float4 a = *(const float4*)wsrc;
      const float4 b4 = *(const float4*)(wsrc + 4);
      wT[0][tid] = a.x; wT[1][tid] = a.y; wT[2][tid] = a.z; wT[3][tid] = a.w;
      wT[4][tid] = b4.x; wT[5][tid] = b4.y; wT[6][tid] = b4.z; wT[7][tid] = b4.w;
    }
    __syncthreads();
#pragma unroll
    for (int kk = 0; kk < 8; ++kk) {
      const float4 w4 = *(const float4*)&wT[kk][c0];
      const float4 xa = *(const float4*)&xcT[kt * 8 + kk][n0t];
      const float4 xb4 = *(const float4*)&xcT[kt * 8 + kk][n0t + 4];
      const float wr[4] = {w4.x, w4.y, w4.z, w4.w};
      const float xr[8] = {xa.x, xa.y, xa.z, xa.w, xb4.x, xb4.y, xb4.z, xb4.w};
#pragma unroll
      for (int r = 0; r < 4; ++r)
#pragma unroll
        for (int e = 0; e < 8; ++e) acc[r][e] = fmaf(wr[r], xr[e], acc[r][e]);
    }
  }

  const float invs = 1.0f / sqrtf(1.0f + 1e-5f);
#pragma unroll
  for (int r = 0; r < 4; ++r) {
    const int cglob = cb * 256 + c0 + r;
    const float s = g5[cglob] * invs;
    const float bb = b5[cglob];
    float mx = -3.0e38f, sm = 0.0f;
#pragma unroll
    for (int e = 0; e < 8; ++e) {
      float v = fmaf(s, acc[r][e], bb);
      v = v > 0.0f ? v : 0.2f * v;
      mx = fmaxf(mx, v);
      sm += v;
    }
    mx = fmaxf(mx, __shfl_xor(mx, 1, 64));
    mx = fmaxf(mx, __shfl_xor(mx, 2, 64));
    sm += __shfl_xor(sm, 1, 64);
    sm += __shfl_xor(sm, 2, 64);
    if (ng == 0) {
      pmax[((size_t)b * 1024 + cglob) * 128 + nb] = mx;
      psum[((size_t)b * 1024 + cglob) * 128 + nb] = sm;
    }
  }
}

// ---- reduce partials -> gfeat [B][2048] = [gmax | gavg] ----
__global__ __launch_bounds__(256) void reduce5(const float* __restrict__ pmax,
                                               const float* __restrict__ psum,
                                               float* __restrict__ gfeat) {
  const int t = blockIdx.x * 256 + threadIdx.x;  // < 8192 = B*1024
  const int b = t >> 10, c = t & 1023;
  const float* pm = pmax + (size_t)t * 128;
  const float* ps = psum + (size_t)t * 128;
  float mx = -3.0e38f, sm = 0.0f;
  for (int i = 0; i < 128; i += 4) {
    const float4 v = *(const float4*)(pm + i);
    mx = fmaxf(mx, fmaxf(fmaxf(v.x, v.y), fmaxf(v.z, v.w)));
    const float4 u = *(const float4*)(ps + i);
    sm += (u.x + u.y) + (u.z + u.w);
  }
  gfeat[b * 2048 + c] = mx;
  gfeat[b * 2048 + 1024 + c] = sm * (1.0f / 4096.0f);
}

// ---- head: y1 = lrelu(bn(gfeat @ Wl1^T)) ----
__global__ __launch_bounds__(256) void head1(const float* __restrict__ gfeat,
                                             const float* __restrict__ Wl1,
                                             const float* __restrict__ g6,
                                             const float* __restrict__ b6,
                                             float* __restrict__ y1g) {
  __shared__ float gf[2048];
  __shared__ float red[256];
  const int tid = threadIdx.x;
  const int cb = blockIdx.x, b = blockIdx.y;
  const float4* gsrc = (const float4*)(gfeat + b * 2048);
  for (int p = tid; p < 512; p += 256) ((float4*)gf)[p] = gsrc[p];
  __syncthreads();
  const int cl = cb * 64 + (tid >> 2);
  const int q = tid & 3;
  const float* wr = Wl1 + (size_t)cl * 2048 + q * 512;
  const float* gq = gf + q * 512;
  float acc = 0.0f;
  for (int k0 = 0; k0 < 512; k0 += 8) {
    const float4 w0 = *(const float4*)(wr + k0);
    const float4 w1 = *(const float4*)(wr + k0 + 4);
    acc = fmaf(w0.x, gq[k0 + 0], acc); acc = fmaf(w0.y, gq[k0 + 1], acc);
    acc = fmaf(w0.z, gq[k0 + 2], acc); acc = fmaf(w0.w, gq[k0 + 3], acc);
    acc = fmaf(w1.x, gq[k0 + 4], acc); acc = fmaf(w1.y, gq[k0 + 5], acc);
    acc = fmaf(w1.z, gq[k0 + 6], acc); acc = fmaf(w1.w, gq[k0 + 7], acc);
  }
  red[tid] = acc;
  __syncthreads();
  if (q == 0) {
    float v = red[tid] + red[tid + 1] + red[tid + 2] + red[tid + 3];
    const float invs = 1.0f / sqrtf(1.0f + 1e-5f);
    v = fmaf(g6[cl] * invs, v, b6[cl]);
    v = v > 0.0f ? v : 0.2f * v;
    y1g[b * 512 + cl] = v;
  }
}

// ---- head: y2, y3, broadcast to [B][N][5] fp32 ----
__global__ __launch_bounds__(256) void head2(
    const float* __restrict__ y1g, const float* __restrict__ Wl2,
    const float* __restrict__ bl2, const float* __restrict__ g7,
    const float* __restrict__ b7, const float* __restrict__ Wl3,
    const float* __restrict__ bl3, float* __restrict__ out) {
  __shared__ float y1s[512];
  __shared__ float y2s[256];
  __shared__ float y3s[5];
  const int b = blockIdx.x;
  const int t = threadIdx.x;
  y1s[t] = y1g[b * 512 + t];
  y1s[t + 256] = y1g[b * 512 + t + 256];
  __syncthreads();
  {
    const float* wr = Wl2 + (size_t)t * 512;
    float acc = 0.0f;
    for (int k0 = 0; k0 < 512; k0 += 8) {
      const float4 w0 = *(const float4*)(wr + k0);
      const float4 w1 = *(const float4*)(wr + k0 + 4);
      acc = fmaf(w0.x, y1s[k0 + 0], acc); acc = fmaf(w0.y, y1s[k0 + 1], acc);
      acc = fmaf(w0.z, y1s[k0 + 2], acc); acc = fmaf(w0.w, y1s[k0 + 3], acc);
      acc = fmaf(w1.x, y1s[k0 + 4], acc); acc = fmaf(w1.y, y1s[k0 + 5], acc);
      acc = fmaf(w1.z, y1s[k0 + 6], acc); acc = fmaf(w1.w, y1s[k0 + 7], acc);
    }
    const float invs = 1.0f / sqrtf(1.0f + 1e-5f);
    float v = acc + bl2[t];
    v = fmaf(g7[t] * invs, v, b7[t]);
    v = v > 0.0f ? v : 0.2f * v;
    y2s[t] = v;
  }
  __syncthreads();
  if (t < 5) {
    const float* wr = Wl3 + (size_t)t * 256;
    float acc = 0.0f;
    for (int k = 0; k < 256; ++k) acc += wr[k] * y2s[k];
    y3s[t] = acc + bl3[t];
  }
  __syncthreads();
  for (int e = t; e < NPT * 5; e += 256)
    out[(size_t)b * (NPT * 5) + e] = y3s[e % 5];
}

extern "C" void kernel_launch(void* const* d_in, const int* in_sizes, int n_in,
                              void* d_out, int out_size, void* d_ws, size_t ws_size,
                              hipStream_t stream) {
  (void)in_sizes; (void)n_in; (void)out_size;
  const float* xyz = (const float*)d_in[0];
  const float* W1  = (const float*)d_in[1];
  const float* g1  = (const float*)d_in[2];
  const float* b1  = (const float*)d_in[3];
  const float* W2  = (const float*)d_in[4];
  const float* g2  = (const float*)d_in[5];
  const float* b2  = (const float*)d_in[6];
  const float* W3  = (const float*)d_in[7];
  const float* g3  = (const float*)d_in[8];
  const float* b3  = (const float*)d_in[9];
  const float* W4  = (const float*)d_in[10];
  const float* g4  = (const float*)d_in[11];
  const float* b4  = (const float*)d_in[12];
  const float* W5  = (const float*)d_in[13];
  const float* g5  = (const float*)d_in[14];
  const float* b5  = (const float*)d_in[15];
  const float* Wl1 = (const float*)d_in[16];
  const float* g6  = (const float*)d_in[17];
  const float* b6  = (const float*)d_in[18];
  const float* Wl2 = (const float*)d_in[19];
  const float* bl2 = (const float*)d_in[20];
  const float* g7  = (const float*)d_in[21];
  const float* b7  = (const float*)d_in[22];
  const float* Wl3 = (const float*)d_in[23];
  const float* bl3 = (const float*)d_in[24];

  char* ws = (char*)d_ws;
  float* x0    = (float*)(ws + 0);         //  524288 B
  float* x1    = (float*)(ws + 524288);    // 8388608 B
  float* x2    = (float*)(ws + 8912896);   // 8388608 B
  float* x3    = (float*)(ws + 17301504);  // 8388608 B
  float* x4    = (float*)(ws + 25690112);  // 16777216 B
  float* sqb   = (float*)(ws + 42467328);  //  131072 B
  int*   idxb  = (int*)  (ws + 42598400);  // 2621440 B
  float* pmx   = (float*)(ws + 45219840);  // 4194304 B
  float* psm   = (float*)(ws + 49414144);  // 4194304 B
  float* gfeat = (float*)(ws + 53608448);  //   65536 B
  float* y1g   = (float*)(ws + 53673984);  //   16384 B
  if (ws_size < 53690368) return;          // need ~51.2 MB scratch

  cvt_xyz<<<128, 256, 0, stream>>>(xyz, x0);

  sq_kernel<3, 4><<<128, 256, 0, stream>>>(x0, sqb);
  knn_kernel<3, 4><<<dim3(64, 8), 256, 0, stream>>>(x0, sqb, idxb);
  edge_kernel<3, 4, 64><<<8192, 256, 0, stream>>>(x0, idxb, W1, g1, b1, x1);

  sq_kernel<64, 64><<<128, 256, 0, stream>>>(x1, sqb);
  knn_kernel<64, 64><<<dim3(64, 8), 256, 0, stream>>>(x1, sqb, idxb);
  edge_kernel<64, 64, 64><<<8192, 256, 0, stream>>>(x1, idxb, W2, g2, b2, x2);

  sq_kernel<64, 64><<<128, 256, 0, stream>>>(x2, sqb);
  knn_kernel<64, 64><<<dim3(64, 8), 256, 0, stream>>>(x2, sqb, idxb);
  edge_kernel<64, 64, 64><<<8192, 256, 0, stream>>>(x2, idxb, W3, g3, b3, x3);

  sq_kernel<64, 64><<<128, 256, 0, stream>>>(x3, sqb);
  knn_kernel<64, 64><<<dim3(64, 8), 256, 0, stream>>>(x3, sqb, idxb);
  edge_kernel<64, 64, 128><<<16384, 256, 0, stream>>>(x3, idxb, W4, g4, b4, x4);

  conv5_kernel<<<dim3(128, 4, 8), 256, 0, stream>>>(x1, x2, x3, x4, W5, g5, b5, pmx, psm);
  reduce5<<<32, 256, 0, stream>>>(pmx, psm, gfeat);
  head1<<<dim3(8, 8), 256, 0, stream>>>(gfeat, Wl1, g6, b6, y1g);
  head2<<<8, 256, 0, stream>>>(y1g, Wl2, bl2, g7, b7, Wl3, bl3, (float*)d_out);
}

// Round 3
// 4039.408 us; speedup vs baseline: 1.1703x; 1.1703x over previous
//
#include <hip/hip_runtime.h>

// DGCNN inference, MI355X gfx950. B=8, N=4096, K=20. fp32 in/out.
// knn layers 2-4: fp16 hi/lo split MFMA distance GEMM, barrier-free j-loop.

constexpr int NB  = 8;
constexpr int NPT = 4096;
constexpr int KNB = 20;

typedef _Float16 half8 __attribute__((ext_vector_type(8)));
typedef float f32x4 __attribute__((ext_vector_type(4)));

// ---- convert xyz fp32 [B][N][3] -> fp32 [B][N][4] (pad 0) ----
__global__ __launch_bounds__(256) void cvt_xyz(const float* __restrict__ xyz,
                                               float* __restrict__ x0) {
  const int t = blockIdx.x * 256 + threadIdx.x;  // < B*N
  float4 v;
  v.x = xyz[t * 3 + 0];
  v.y = xyz[t * 3 + 1];
  v.z = xyz[t * 3 + 2];
  v.w = 0.0f;
  *(float4*)(x0 + (size_t)t * 4) = v;
}

// ---- sq norms + fp16 hi/lo split of a [B*N][64] fp32 feature map ----
// 4 threads per point, 16 ch each. grid 512x256.
__global__ __launch_bounds__(256) void sqsplit(const float* __restrict__ x,
                                               float* __restrict__ sqo,
                                               unsigned short* __restrict__ xhi,
                                               unsigned short* __restrict__ xlo) {
  const int t = blockIdx.x * 256 + threadIdx.x;  // < B*N*4
  const int p = t >> 2, c = t & 3;
  const float* src = x + (size_t)p * 64 + c * 16;
  float s = 0.0f;
  unsigned short hb[16], lb[16];
#pragma unroll
  for (int e = 0; e < 16; e += 4) {
    const float4 v = *(const float4*)(src + e);
    const float vv[4] = {v.x, v.y, v.z, v.w};
#pragma unroll
    for (int u = 0; u < 4; ++u) {
      const float f = vv[u];
      s = fmaf(f, f, s);
      const _Float16 h = (_Float16)f;
      const _Float16 l = (_Float16)(f - (float)h);
      hb[e + u] = __builtin_bit_cast(unsigned short, h);
      lb[e + u] = __builtin_bit_cast(unsigned short, l);
    }
  }
  unsigned short* dh = xhi + (size_t)p * 64 + c * 16;
  unsigned short* dl = xlo + (size_t)p * 64 + c * 16;
  *(uint4*)dh = *(uint4*)hb;
  *(uint4*)(dh + 8) = *(uint4*)(hb + 8);
  *(uint4*)dl = *(uint4*)lb;
  *(uint4*)(dl + 8) = *(uint4*)(lb + 8);
  s += __shfl_xor(s, 1, 64);
  s += __shfl_xor(s, 2, 64);
  if (c == 0) sqo[p] = s;
}

// ---- wave-cooperative sorted top-20 insert ----
// List for one row distributed over lanes 0..19 (ascending). dd = this lane's
// candidate (j = j0 + lane). Mutates register refs ld/lj.
__device__ __forceinline__ void sel_update(float dd, int j0, int lane,
                                           float& ld, int& lj) {
  unsigned long long cm = __ballot(dd < __shfl(ld, 19, 64));
  while (cm) {
    const int bit = __builtin_ctzll(cm);
    cm &= cm - 1;
    const float nd = __shfl(dd, bit, 64);
    const int nj = j0 + bit;
    const float cur = __shfl(ld, 19, 64);
    if (nd < cur) {  // wave-uniform
      const bool gt = (lane < 20) && (ld > nd);
      const unsigned long long gm = __ballot(gt);
      const int pos = __builtin_ctzll(gm);
      const float sd = __shfl_up(ld, 1, 64);
      const int sj = __shfl_up(lj, 1, 64);
      if (lane < 20) {
        if (lane > pos)       { ld = sd; lj = sj; }
        else if (lane == pos) { ld = nd; lj = nj; }
      }
    }
  }
}

// ---- knn layer 1 (D=3): direct per-lane distances, no LDS, no barriers ----
// grid (64, 8) x 256. Wave owns 16 i-rows; lane l handles candidate j0+l.
__global__ __launch_bounds__(256) void knn3(const float* __restrict__ x0,
                                            int* __restrict__ idxout) {
  const int b = blockIdx.y, i0 = blockIdx.x * 64;
  const int tid = threadIdx.x, w = tid >> 6, lane = tid & 63;
  const float* xb = x0 + (size_t)b * (NPT * 4);
  float4 xi[16];
#pragma unroll
  for (int s = 0; s < 16; ++s)
    xi[s] = *(const float4*)(xb + (size_t)(i0 + w * 16 + s) * 4);

  float lst_d[16];
  int lst_j[16];
#pragma unroll
  for (int s = 0; s < 16; ++s) { lst_d[s] = 3.0e38f; lst_j[s] = 0; }

  for (int jt = 0; jt < NPT / 64; ++jt) {
    const int j0 = jt * 64;
    const float4 xj = *(const float4*)(xb + (size_t)(j0 + lane) * 4);
#pragma unroll
    for (int s = 0; s < 16; ++s) {
      const float dx = xj.x - xi[s].x;
      const float dy = xj.y - xi[s].y;
      const float dz = xj.z - xi[s].z;
      const float dd = fmaf(dx, dx, fmaf(dy, dy, dz * dz));
      sel_update(dd, j0, lane, lst_d[s], lst_j[s]);
    }
  }
#pragma unroll
  for (int s = 0; s < 16; ++s) {
    const int i = i0 + w * 16 + s;
    if (lane < 20) idxout[((size_t)(b * NPT + i)) * KNB + lane] = lst_j[s];
  }
}

// ---- knn layers 2-4 (D=64): fp16x2-split MFMA, barrier-free ----
// grid (64, 8) x 256. Wave w owns i-rows i0+w*16..+15 (A-frags in registers,
// loaded once). B-frags loaded straight from global per 64-wide j-tile.
// C (inner products) -> per-wave LDS transpose -> ballot top-20.
// Selection metric: dd = sqj - 2*inner  (sqi is per-row constant).
__global__ __launch_bounds__(256) void knn_mfma(
    const unsigned short* __restrict__ xhi16,
    const unsigned short* __restrict__ xlo16,
    const float* __restrict__ sqn, int* __restrict__ idxout) {
  const int b = blockIdx.y, i0 = blockIdx.x * 64;
  const int tid = threadIdx.x, w = tid >> 6, lane = tid & 63;
  const int l15 = lane & 15, quad = lane >> 4;
  __shared__ float dist[4][16][68];  // per-wave region; stride 68: 2-way banks

  const half8* Hb = (const half8*)(xhi16 + (size_t)b * NPT * 64);
  const half8* Lb = (const half8*)(xlo16 + (size_t)b * NPT * 64);
  const float* sqb = sqn + b * NPT;

  // A-frags: A[m=l15][k=quad*8+j], k-chunks kc*32 -> h8 index p*8 + kc*4 + quad
  const int ia = i0 + w * 16 + l15;
  const half8 ah0 = Hb[(size_t)ia * 8 + quad];
  const half8 ah1 = Hb[(size_t)ia * 8 + 4 + quad];
  const half8 al0 = Lb[(size_t)ia * 8 + quad];
  const half8 al1 = Lb[(size_t)ia * 8 + 4 + quad];

  float lst_d[16];
  int lst_j[16];
#pragma unroll
  for (int s = 0; s < 16; ++s) { lst_d[s] = 3.0e38f; lst_j[s] = 0; }

  for (int jt = 0; jt < NPT / 64; ++jt) {
    const int j0 = jt * 64;
    const float sqj = sqb[j0 + lane];
    f32x4 acc[4];
#pragma unroll
    for (int nj = 0; nj < 4; ++nj) {
      const int jb = j0 + nj * 16 + l15;
      const half8 bh0 = Hb[(size_t)jb * 8 + quad];
      const half8 bh1 = Hb[(size_t)jb * 8 + 4 + quad];
      const half8 bl0 = Lb[(size_t)jb * 8 + quad];
      const half8 bl1 = Lb[(size_t)jb * 8 + 4 + quad];
      f32x4 a = {0.0f, 0.0f, 0.0f, 0.0f};
      a = __builtin_amdgcn_mfma_f32_16x16x32_f16(al0, bh0, a, 0, 0, 0);
      a = __builtin_amdgcn_mfma_f32_16x16x32_f16(al1, bh1, a, 0, 0, 0);
      a = __builtin_amdgcn_mfma_f32_16x16x32_f16(ah0, bl0, a, 0, 0, 0);
      a = __builtin_amdgcn_mfma_f32_16x16x32_f16(ah1, bl1, a, 0, 0, 0);
      a = __builtin_amdgcn_mfma_f32_16x16x32_f16(ah0, bh0, a, 0, 0, 0);
      a = __builtin_amdgcn_mfma_f32_16x16x32_f16(ah1, bh1, a, 0, 0, 0);
      acc[nj] = a;
    }
    // C layout: row = quad*4+reg, col = l15 (tile nj -> global col nj*16+l15)
#pragma unroll
    for (int nj = 0; nj < 4; ++nj)
#pragma unroll
      for (int r = 0; r < 4; ++r)
        dist[w][quad * 4 + r][nj * 16 + l15] = acc[nj][r];
    // wave-private LDS; DS pipe is in-order per wave, compiler inserts lgkmcnt.
#pragma unroll
    for (int s = 0; s < 16; ++s) {
      const float dd = fmaf(-2.0f, dist[w][s][lane], sqj);
      sel_update(dd, j0, lane, lst_d[s], lst_j[s]);
    }
  }
#pragma unroll
  for (int s = 0; s < 16; ++s) {
    const int i = i0 + w * 16 + s;
    if (lane < 20) idxout[((size_t)(b * NPT + i)) * KNB + lane] = lst_j[s];
  }
}

// ---- EdgeConv: conv1x1 + BN + LeakyReLU + max over k neighbors ----
template <int DIN, int DS, int COUT>
__global__ __launch_bounds__(256) void edge_kernel(
    const float* __restrict__ x, const int* __restrict__ idx,
    const float* __restrict__ W, const float* __restrict__ g,
    const float* __restrict__ bia, float* __restrict__ out) {
  constexpr int CG = COUT / 64;
  const int lane = threadIdx.x & 63;
  const int wglob = blockIdx.x * 4 + (threadIdx.x >> 6);
  const int n_lin = __builtin_amdgcn_readfirstlane(wglob / CG);  // b*N+n
  const int cg = __builtin_amdgcn_readfirstlane(wglob % CG);
  const int b = n_lin >> 12;
  const int n = n_lin & (NPT - 1);
  const int c = cg * 64 + lane;

  const float* wrow = W + (size_t)c * (2 * DIN);
  const float invs = 1.0f / sqrtf(1.0f + 1e-5f);
  const float s = g[c] * invs;
  const float bias = bia[c];

  const float* xb = x + (size_t)b * (NPT * DS);
  const float* xi = xb + (size_t)n * DS;

  float wa[DIN];
  float base = 0.0f;
  if constexpr (DIN == 3) {
    wa[0] = wrow[0]; wa[1] = wrow[1]; wa[2] = wrow[2];
    const float wb0 = wrow[3], wb1 = wrow[4], wb2 = wrow[5];
    const float4 vi = *(const float4*)xi;
    base = (wb0 - wa[0]) * vi.x + (wb1 - wa[1]) * vi.y + (wb2 - wa[2]) * vi.z;
  } else {
#pragma unroll
    for (int d0 = 0; d0 < DIN; d0 += 4) {
      const float4 w4 = *(const float4*)(wrow + d0);
      wa[d0 + 0] = w4.x; wa[d0 + 1] = w4.y; wa[d0 + 2] = w4.z; wa[d0 + 3] = w4.w;
    }
#pragma unroll
    for (int d0 = 0; d0 < DIN; d0 += 4) {
      const float4 wb4 = *(const float4*)(wrow + DIN + d0);
      const float4 v0 = *(const float4*)(xi + d0);
      base += (wb4.x - wa[d0 + 0]) * v0.x + (wb4.y - wa[d0 + 1]) * v0.y +
              (wb4.z - wa[d0 + 2]) * v0.z + (wb4.w - wa[d0 + 3]) * v0.w;
    }
  }
  base = s * base + bias;

  const int* ip = idx + (size_t)n_lin * KNB;
  float m = -3.0e38f;
  for (int k = 0; k < KNB; ++k) {
    const int j = __builtin_amdgcn_readfirstlane(ip[k]);
    const float* xj = xb + (size_t)j * DS;
    float acc = 0.0f;
    if constexpr (DIN == 3) {
      const float4 v = *(const float4*)xj;
      acc = wa[0] * v.x + wa[1] * v.y + wa[2] * v.z;
    } else {
#pragma unroll
      for (int d0 = 0; d0 < DIN; d0 += 8) {
        const float4 v0 = *(const float4*)(xj + d0);
        const float4 v1 = *(const float4*)(xj + d0 + 4);
        acc += wa[d0 + 0] * v0.x + wa[d0 + 1] * v0.y + wa[d0 + 2] * v0.z +
               wa[d0 + 3] * v0.w + wa[d0 + 4] * v1.x + wa[d0 + 5] * v1.y +
               wa[d0 + 6] * v1.z + wa[d0 + 7] * v1.w;
      }
    }
    float v = s * acc + base;
    v = v > 0.0f ? v : 0.2f * v;
    m = fmaxf(m, v);
  }
  out[(size_t)n_lin * COUT + c] = m;
}

// ---- conv5 (320->1024) + BN + lrelu, fused partial max/sum pooling ----
__global__ __launch_bounds__(256) void conv5_kernel(
    const float* __restrict__ x1, const float* __restrict__ x2,
    const float* __restrict__ x3, const float* __restrict__ x4,
    const float* __restrict__ W5, const float* __restrict__ g5,
    const float* __restrict__ b5, float* __restrict__ pmax,
    float* __restrict__ psum) {
  __shared__ float xcT[320][32];
  __shared__ float wT[8][256];
  const int nb = blockIdx.x, cb = blockIdx.y, b = blockIdx.z;
  const int tid = threadIdx.x;
  const int n0 = nb * 32;

#pragma unroll
  for (int p = 0; p < 10; ++p) {
    const int q = tid + p * 256;  // [0,2560) float4s
    const int nloc = q / 80;
    const int kg = (q % 80) * 4;
    const float* src;
    int koff;
    if (kg < 64)       { src = x1 + ((size_t)(b * NPT + n0 + nloc)) * 64;  koff = kg; }
    else if (kg < 128) { src = x2 + ((size_t)(b * NPT + n0 + nloc)) * 64;  koff = kg - 64; }
    else if (kg < 192) { src = x3 + ((size_t)(b * NPT + n0 + nloc)) * 64;  koff = kg - 128; }
    else               { src = x4 + ((size_t)(b * NPT + n0 + nloc)) * 128; koff = kg - 192; }
    const float4 v = *(const float4*)(src + koff);
    xcT[kg + 0][nloc] = v.x; xcT[kg + 1][nloc] = v.y;
    xcT[kg + 2][nloc] = v.z; xcT[kg + 3][nloc] = v.w;
  }

  const int cg = tid >> 2, ng = tid & 3;
  const int c0 = cg * 4, n0t = ng * 8;
  float acc[4][8];
#pragma unroll
  for (int r = 0; r < 4; ++r)
#pragma unroll
    for (int e = 0; e < 8; ++e) acc[r][e] = 0.0f;

  for (int kt = 0; kt < 40; ++kt) {
    __syncthreads();
    {
      const float* wsrc = W5 + (size_t)(cb * 256 + tid) * 320 + kt * 8;
      const float4 a = *(const float4*)wsrc;
      const float4 b4 = *(const float4*)(wsrc + 4);
      wT[0][tid] = a.x; wT[1][tid] = a.y; wT[2][tid] = a.z; wT[3][tid] = a.w;
      wT[4][tid] = b4.x; wT[5][tid] = b4.y; wT[6][tid] = b4.z; wT[7][tid] = b4.w;
    }
    __syncthreads();
#pragma unroll
    for (int kk = 0; kk < 8; ++kk) {
      const float4 w4 = *(const float4*)&wT[kk][c0];
      const float4 xa = *(const float4*)&xcT[kt * 8 + kk][n0t];
      const float4 xb4 = *(const float4*)&xcT[kt * 8 + kk][n0t + 4];
      const float wr[4] = {w4.x, w4.y, w4.z, w4.w};
      const float xr[8] = {xa.x, xa.y, xa.z, xa.w, xb4.x, xb4.y, xb4.z, xb4.w};
#pragma unroll
      for (int r = 0; r < 4; ++r)
#pragma unroll
        for (int e = 0; e < 8; ++e) acc[r][e] = fmaf(wr[r], xr[e], acc[r][e]);
    }
  }

  const float invs = 1.0f / sqrtf(1.0f + 1e-5f);
#pragma unroll
  for (int r = 0; r < 4; ++r) {
    const int cglob = cb * 256 + c0 + r;
    const float s = g5[cglob] * invs;
    const float bb = b5[cglob];
    float mx = -3.0e38f, sm = 0.0f;
#pragma unroll
    for (int e = 0; e < 8; ++e) {
      float v = fmaf(s, acc[r][e], bb);
      v = v > 0.0f ? v : 0.2f * v;
      mx = fmaxf(mx, v);
      sm += v;
    }
    mx = fmaxf(mx, __shfl_xor(mx, 1, 64));
    mx = fmaxf(mx, __shfl_xor(mx, 2, 64));
    sm += __shfl_xor(sm, 1, 64);
    sm += __shfl_xor(sm, 2, 64);
    if (ng == 0) {
      pmax[((size_t)b * 1024 + cglob) * 128 + nb] = mx;
      psum[((size_t)b * 1024 + cglob) * 128 + nb] = sm;
    }
  }
}

// ---- reduce partials -> gfeat [B][2048] = [gmax | gavg] ----
__global__ __launch_bounds__(256) void reduce5(const float* __restrict__ pmax,
                                               const float* __restrict__ psum,
                                               float* __restrict__ gfeat) {
  const int t = blockIdx.x * 256 + threadIdx.x;  // < 8192 = B*1024
  const int b = t >> 10, c = t & 1023;
  const float* pm = pmax + (size_t)t * 128;
  const float* ps = psum + (size_t)t * 128;
  float mx = -3.0e38f, sm = 0.0f;
  for (int i = 0; i < 128; i += 4) {
    const float4 v = *(const float4*)(pm + i);
    mx = fmaxf(mx, fmaxf(fmaxf(v.x, v.y), fmaxf(v.z, v.w)));
    const float4 u = *(const float4*)(ps + i);
    sm += (u.x + u.y) + (u.z + u.w);
  }
  gfeat[b * 2048 + c] = mx;
  gfeat[b * 2048 + 1024 + c] = sm * (1.0f / 4096.0f);
}

// ---- head: y1 = lrelu(bn(gfeat @ Wl1^T)) ----
__global__ __launch_bounds__(256) void head1(const float* __restrict__ gfeat,
                                             const float* __restrict__ Wl1,
                                             const float* __restrict__ g6,
                                             const float* __restrict__ b6,
                                             float* __restrict__ y1g) {
  __shared__ float gf[2048];
  __shared__ float red[256];
  const int tid = threadIdx.x;
  const int cb = blockIdx.x, b = blockIdx.y;
  const float4* gsrc = (const float4*)(gfeat + b * 2048);
  for (int p = tid; p < 512; p += 256) ((float4*)gf)[p] = gsrc[p];
  __syncthreads();
  const int cl = cb * 64 + (tid >> 2);
  const int q = tid & 3;
  const float* wr = Wl1 + (size_t)cl * 2048 + q * 512;
  const float* gq = gf + q * 512;
  float acc = 0.0f;
  for (int k0 = 0; k0 < 512; k0 += 8) {
    const float4 w0 = *(const float4*)(wr + k0);
    const float4 w1 = *(const float4*)(wr + k0 + 4);
    acc = fmaf(w0.x, gq[k0 + 0], acc); acc = fmaf(w0.y, gq[k0 + 1], acc);
    acc = fmaf(w0.z, gq[k0 + 2], acc); acc = fmaf(w0.w, gq[k0 + 3], acc);
    acc = fmaf(w1.x, gq[k0 + 4], acc); acc = fmaf(w1.y, gq[k0 + 5], acc);
    acc = fmaf(w1.z, gq[k0 + 6], acc); acc = fmaf(w1.w, gq[k0 + 7], acc);
  }
  red[tid] = acc;
  __syncthreads();
  if (q == 0) {
    float v = red[tid] + red[tid + 1] + red[tid + 2] + red[tid + 3];
    const float invs = 1.0f / sqrtf(1.0f + 1e-5f);
    v = fmaf(g6[cl] * invs, v, b6[cl]);
    v = v > 0.0f ? v : 0.2f * v;
    y1g[b * 512 + cl] = v;
  }
}

// ---- head: y2, y3, broadcast to [B][N][5] fp32 ----
__global__ __launch_bounds__(256) void head2(
    const float* __restrict__ y1g, const float* __restrict__ Wl2,
    const float* __restrict__ bl2, const float* __restrict__ g7,
    const float* __restrict__ b7, const float* __restrict__ Wl3,
    const float* __restrict__ bl3, float* __restrict__ out) {
  __shared__ float y1s[512];
  __shared__ float y2s[256];
  __shared__ float y3s[5];
  const int b = blockIdx.x;
  const int t = threadIdx.x;
  y1s[t] = y1g[b * 512 + t];
  y1s[t + 256] = y1g[b * 512 + t + 256];
  __syncthreads();
  {
    const float* wr = Wl2 + (size_t)t * 512;
    float acc = 0.0f;
    for (int k0 = 0; k0 < 512; k0 += 8) {
      const float4 w0 = *(const float4*)(wr + k0);
      const float4 w1 = *(const float4*)(wr + k0 + 4);
      acc = fmaf(w0.x, y1s[k0 + 0], acc); acc = fmaf(w0.y, y1s[k0 + 1], acc);
      acc = fmaf(w0.z, y1s[k0 + 2], acc); acc = fmaf(w0.w, y1s[k0 + 3], acc);
      acc = fmaf(w1.x, y1s[k0 + 4], acc); acc = fmaf(w1.y, y1s[k0 + 5], acc);
      acc = fmaf(w1.z, y1s[k0 + 6], acc); acc = fmaf(w1.w, y1s[k0 + 7], acc);
    }
    const float invs = 1.0f / sqrtf(1.0f + 1e-5f);
    float v = acc + bl2[t];
    v = fmaf(g7[t] * invs, v, b7[t]);
    v = v > 0.0f ? v : 0.2f * v;
    y2s[t] = v;
  }
  __syncthreads();
  if (t < 5) {
    const float* wr = Wl3 + (size_t)t * 256;
    float acc = 0.0f;
    for (int k = 0; k < 256; ++k) acc += wr[k] * y2s[k];
    y3s[t] = acc + bl3[t];
  }
  __syncthreads();
  for (int e = t; e < NPT * 5; e += 256)
    out[(size_t)b * (NPT * 5) + e] = y3s[e % 5];
}

extern "C" void kernel_launch(void* const* d_in, const int* in_sizes, int n_in,
                              void* d_out, int out_size, void* d_ws, size_t ws_size,
                              hipStream_t stream) {
  (void)in_sizes; (void)n_in; (void)out_size;
  const float* xyz = (const float*)d_in[0];
  const float* W1  = (const float*)d_in[1];
  const float* g1  = (const float*)d_in[2];
  const float* b1  = (const float*)d_in[3];
  const float* W2  = (const float*)d_in[4];
  const float* g2  = (const float*)d_in[5];
  const float* b2  = (const float*)d_in[6];
  const float* W3  = (const float*)d_in[7];
  const float* g3  = (const float*)d_in[8];
  const float* b3  = (const float*)d_in[9];
  const float* W4  = (const float*)d_in[10];
  const float* g4  = (const float*)d_in[11];
  const float* b4  = (const float*)d_in[12];
  const float* W5  = (const float*)d_in[13];
  const float* g5  = (const float*)d_in[14];
  const float* b5  = (const float*)d_in[15];
  const float* Wl1 = (const float*)d_in[16];
  const float* g6  = (const float*)d_in[17];
  const float* b6  = (const float*)d_in[18];
  const float* Wl2 = (const float*)d_in[19];
  const float* bl2 = (const float*)d_in[20];
  const float* g7  = (const float*)d_in[21];
  const float* b7  = (const float*)d_in[22];
  const float* Wl3 = (const float*)d_in[23];
  const float* bl3 = (const float*)d_in[24];

  char* ws = (char*)d_ws;
  float* x0    = (float*)(ws + 0);         //  524288 B
  float* x1    = (float*)(ws + 524288);    // 8388608 B
  float* x2    = (float*)(ws + 8912896);   // 8388608 B
  float* x3    = (float*)(ws + 17301504);  // 8388608 B
  float* x4    = (float*)(ws + 25690112);  // 16777216 B
  float* sqb   = (float*)(ws + 42467328);  //  131072 B
  int*   idxb  = (int*)  (ws + 42598400);  // 2621440 B
  float* pmx   = (float*)(ws + 45219840);  // 4194304 B (aliased: xhi during knn)
  float* psm   = (float*)(ws + 49414144);  // 4194304 B (aliased: xlo during knn)
  float* gfeat = (float*)(ws + 53608448);  //   65536 B
  float* y1g   = (float*)(ws + 53673984);  //   16384 B
  if (ws_size < 53690368) return;          // need ~51.2 MB scratch

  unsigned short* xhi = (unsigned short*)pmx;  // 4 MB, used before conv5
  unsigned short* xlo = (unsigned short*)psm;  // 4 MB, used before conv5

  cvt_xyz<<<128, 256, 0, stream>>>(xyz, x0);

  knn3<<<dim3(64, 8), 256, 0, stream>>>(x0, idxb);
  edge_kernel<3, 4, 64><<<8192, 256, 0, stream>>>(x0, idxb, W1, g1, b1, x1);

  sqsplit<<<512, 256, 0, stream>>>(x1, sqb, xhi, xlo);
  knn_mfma<<<dim3(64, 8), 256, 0, stream>>>(xhi, xlo, sqb, idxb);
  edge_kernel<64, 64, 64><<<8192, 256, 0, stream>>>(x1, idxb, W2, g2, b2, x2);

  sqsplit<<<512, 256, 0, stream>>>(x2, sqb, xhi, xlo);
  knn_mfma<<<dim3(64, 8), 256, 0, stream>>>(xhi, xlo, sqb, idxb);
  edge_kernel<64, 64, 64><<<8192, 256, 0, stream>>>(x2, idxb, W3, g3, b3, x3);

  sqsplit<<<512, 256, 0, stream>>>(x3, sqb, xhi, xlo);
  knn_mfma<<<dim3(64, 8), 256, 0, stream>>>(xhi, xlo, sqb, idxb);
  edge_kernel<64, 64, 128><<<16384, 256, 0, stream>>>(x3, idxb, W4, g4, b4, x4);

  conv5_kernel<<<dim3(128, 4, 8), 256, 0, stream>>>(x1, x2, x3, x4, W5, g5, b5, pmx, psm);
  reduce5<<<32, 256, 0, stream>>>(pmx, psm, gfeat);
  head1<<<dim3(8, 8), 256, 0, stream>>>(gfeat, Wl1, g6, b6, y1g);
  head2<<<8, 256, 0, stream>>>(y1g, Wl2, bl2, g7, b7, Wl3, bl3, (float*)d_out);
}

// Round 4
// 2873.181 us; speedup vs baseline: 1.6454x; 1.4059x over previous
//
#include <hip/hip_runtime.h>

// DGCNN inference, MI355X gfx950. B=8, N=4096, K=20. fp32 in/out.
// knn: MFMA distance GEMM + filter/append/bitonic-compact top-20 (set semantics).

constexpr int NB  = 8;
constexpr int NPT = 4096;
constexpr int KNB = 20;

typedef _Float16 half8 __attribute__((ext_vector_type(8)));
typedef float f32x4 __attribute__((ext_vector_type(4)));

// monotone float->uint map (order-preserving, handles negatives)
__device__ __forceinline__ unsigned int fmono(float f) {
  unsigned int u = __float_as_uint(f);
  return u ^ ((unsigned int)(((int)u) >> 31) | 0x80000000u);
}

// ---- wave-wide compaction: exact 20 smallest of rowbuf[0..n), n <= 128 ----
// Bitonic sort A(asc) + B(desc), elementwise min -> bitonic merge -> ascending
// 64 smallest in lanes 0..63; top-20 in lanes 0..19. Updates tau (20th key).
// BUF_OFF: byte offset of buffer region in dynamic LDS. Layout:
//   buf:  u64 [64 rows][84]   at BUF_OFF
//   tau:  u64 [64 rows]       at BUF_OFF + 43008
//   cnt:  int [64 rows]       at BUF_OFF + 43520
template <int BUF_OFF>
__device__ __attribute__((noinline)) unsigned long long compact_row(
    int w, int s, int lane, bool wb) {
  extern __shared__ char smem[];
  unsigned long long* buf =
      (unsigned long long*)(smem + BUF_OFF) + (w * 16 + s) * 84;
  unsigned long long* tauA = (unsigned long long*)(smem + BUF_OFF + 43008);
  int* cntA = (int*)(smem + BUF_OFF + 43520);
  const unsigned long long INFK = ~0ull;
  const int n = cntA[w * 16 + s];
  unsigned long long a = (lane < n) ? buf[lane] : INFK;
  unsigned long long c = (lane + 64 < n) ? buf[lane + 64] : INFK;
#pragma unroll
  for (int k = 2; k <= 64; k <<= 1) {
#pragma unroll
    for (int j = k >> 1; j > 0; j >>= 1) {
      const bool tm = (((lane & k) == 0) == ((lane & j) == 0));
      const unsigned long long oa = __shfl_xor(a, j, 64);
      a = ((a < oa) == tm) ? a : oa;  // ascending network
      const unsigned long long oc = __shfl_xor(c, j, 64);
      c = ((c < oc) == tm) ? oc : c;  // inverted comparators -> descending
    }
  }
  unsigned long long m = a < c ? a : c;  // bitonic: 64 smallest of 128
#pragma unroll
  for (int j = 32; j > 0; j >>= 1) {  // merge to ascending
    const unsigned long long o = __shfl_xor(m, j, 64);
    const bool low = (lane & j) == 0;
    m = ((m < o) == low) ? m : o;
  }
  const unsigned long long t19 = __shfl(m, 19, 64);
  if (wb) {
    if (lane < 20) buf[lane] = m;
    if (lane == 0) { tauA[w * 16 + s] = t19; cntA[w * 16 + s] = 20; }
  } else {
    if (lane == 0) tauA[w * 16 + s] = t19;
  }
  return m;
}

// per-tile filter + parallel append (cap 84; compact-before-append + refilter)
template <int BUF_OFF>
__device__ __forceinline__ void sel_tile(unsigned long long key, int w, int s,
                                         int lane) {
  extern __shared__ char smem[];
  unsigned long long* bufB = (unsigned long long*)(smem + BUF_OFF);
  unsigned long long* tauB = (unsigned long long*)(smem + BUF_OFF + 43008);
  int* cntB = (int*)(smem + BUF_OFF + 43520);
  const int rs = w * 16 + s;
  const unsigned long long tv = tauB[rs];
  bool pass = key < tv;
  unsigned long long mask = __ballot(pass);
  if (mask != 0) {
    int cn = __builtin_amdgcn_readfirstlane(cntB[rs]);
    int pc = (int)__popcll(mask);
    if (cn + pc > 84) {
      compact_row<BUF_OFF>(w, s, lane, true);
      cn = 20;
      const unsigned long long tv2 = tauB[rs];  // tightened
      pass = key < tv2;
      mask = __ballot(pass);
      pc = (int)__popcll(mask);
    }
    if (pass) {
      const int off = (int)__popcll(mask & ((1ull << lane) - 1));
      bufB[rs * 84 + cn + off] = key;
    }
    if (lane == 0) cntB[rs] = cn + pc;
  }
}

// ---- convert xyz fp32 [B][N][3] -> fp32 [B][N][4] (pad 0) ----
__global__ __launch_bounds__(256) void cvt_xyz(const float* __restrict__ xyz,
                                               float* __restrict__ x0) {
  const int t = blockIdx.x * 256 + threadIdx.x;  // < B*N
  float4 v;
  v.x = xyz[t * 3 + 0];
  v.y = xyz[t * 3 + 1];
  v.z = xyz[t * 3 + 2];
  v.w = 0.0f;
  *(float4*)(x0 + (size_t)t * 4) = v;
}

// ---- sq norms + fp16 hi/lo split of a [B*N][64] fp32 feature map ----
__global__ __launch_bounds__(256) void sqsplit(const float* __restrict__ x,
                                               float* __restrict__ sqo,
                                               unsigned short* __restrict__ xhi,
                                               unsigned short* __restrict__ xlo) {
  const int t = blockIdx.x * 256 + threadIdx.x;  // < B*N*4
  const int p = t >> 2, c = t & 3;
  const float* src = x + (size_t)p * 64 + c * 16;
  float s = 0.0f;
  unsigned short hb[16], lb[16];
#pragma unroll
  for (int e = 0; e < 16; e += 4) {
    const float4 v = *(const float4*)(src + e);
    const float vv[4] = {v.x, v.y, v.z, v.w};
#pragma unroll
    for (int u = 0; u < 4; ++u) {
      const float f = vv[u];
      s = fmaf(f, f, s);
      const _Float16 h = (_Float16)f;
      const _Float16 l = (_Float16)(f - (float)h);
      hb[e + u] = __builtin_bit_cast(unsigned short, h);
      lb[e + u] = __builtin_bit_cast(unsigned short, l);
    }
  }
  unsigned short* dh = xhi + (size_t)p * 64 + c * 16;
  unsigned short* dl = xlo + (size_t)p * 64 + c * 16;
  *(uint4*)dh = *(uint4*)hb;
  *(uint4*)(dh + 8) = *(uint4*)(hb + 8);
  *(uint4*)dl = *(uint4*)lb;
  *(uint4*)(dl + 8) = *(uint4*)(lb + 8);
  s += __shfl_xor(s, 1, 64);
  s += __shfl_xor(s, 2, 64);
  if (c == 0) sqo[p] = s;
}

// ---- knn layer 1 (D=3): direct distances + filter/append selection ----
// dyn LDS: buf/tau/cnt only (BUF_OFF=0), 43776 B.
__global__ __launch_bounds__(256) void knn3(const float* __restrict__ x0,
                                            int* __restrict__ idxout) {
  extern __shared__ char smem[];
  const int b = blockIdx.y, i0 = blockIdx.x * 64;
  const int tid = threadIdx.x, w = tid >> 6, lane = tid & 63;
  const float* xb = x0 + (size_t)b * (NPT * 4);
  float4 xi[16];
#pragma unroll
  for (int s = 0; s < 16; ++s)
    xi[s] = *(const float4*)(xb + (size_t)(i0 + w * 16 + s) * 4);

  {  // init tau/cnt (wave-private rows, no barrier)
    unsigned long long* tauB = (unsigned long long*)(smem + 43008);
    int* cntB = (int*)(smem + 43520);
    if (lane < 16) { tauB[w * 16 + lane] = ~0ull; cntB[w * 16 + lane] = 0; }
  }

  for (int jt = 0; jt < NPT / 64; ++jt) {
    const int j0 = jt * 64;
    const float4 xj = *(const float4*)(xb + (size_t)(j0 + lane) * 4);
#pragma unroll
    for (int s = 0; s < 16; ++s) {
      const float dx = xj.x - xi[s].x;
      const float dy = xj.y - xi[s].y;
      const float dz = xj.z - xi[s].z;
      const float dd = fmaf(dx, dx, fmaf(dy, dy, dz * dz));
      const unsigned long long key =
          ((unsigned long long)fmono(dd) << 32) | (unsigned int)(j0 + lane);
      sel_tile<0>(key, w, s, lane);
    }
  }
#pragma unroll 1
  for (int s = 0; s < 16; ++s) {
    const unsigned long long m = compact_row<0>(w, s, lane, false);
    const int i = i0 + w * 16 + s;
    if (lane < 20)
      idxout[((size_t)(b * NPT + i)) * KNB + lane] = (int)(unsigned int)m;
  }
}

// ---- knn layers 2-4 (D=64): fp16x2-split MFMA + filter/append selection ----
// dyn LDS: dist f32[4][16][66] @0 (16896), buf @16896 (43008), tau, cnt.
// Total 60672 B. Stride 66: conflict-free writes (quad spacing 8) and reads.
constexpr int KD_OFF = 16896;
__global__ __launch_bounds__(256) void knn_mfma(
    const unsigned short* __restrict__ xhi16,
    const unsigned short* __restrict__ xlo16,
    const float* __restrict__ sqn, int* __restrict__ idxout) {
  extern __shared__ char smem[];
  const int b = blockIdx.y, i0 = blockIdx.x * 64;
  const int tid = threadIdx.x, w = tid >> 6, lane = tid & 63;
  const int l15 = lane & 15, quad = lane >> 4;
  float* D = (float*)smem;

  const half8* Hb = (const half8*)(xhi16 + (size_t)b * NPT * 64);
  const half8* Lb = (const half8*)(xlo16 + (size_t)b * NPT * 64);
  const float* sqb = sqn + b * NPT;

  // A-frags: A[m=l15][k=quad*8+j]
  const int ia = i0 + w * 16 + l15;
  const half8 ah0 = Hb[(size_t)ia * 8 + quad];
  const half8 ah1 = Hb[(size_t)ia * 8 + 4 + quad];
  const half8 al0 = Lb[(size_t)ia * 8 + quad];
  const half8 al1 = Lb[(size_t)ia * 8 + 4 + quad];

  {  // init tau/cnt
    unsigned long long* tauB = (unsigned long long*)(smem + KD_OFF + 43008);
    int* cntB = (int*)(smem + KD_OFF + 43520);
    if (lane < 16) { tauB[w * 16 + lane] = ~0ull; cntB[w * 16 + lane] = 0; }
  }

  for (int jt = 0; jt < NPT / 64; ++jt) {
    const int j0 = jt * 64;
    const float sqj = sqb[j0 + lane];
    f32x4 acc[4];
#pragma unroll
    for (int nj = 0; nj < 4; ++nj) {
      const int jb = j0 + nj * 16 + l15;
      const half8 bh0 = Hb[(size_t)jb * 8 + quad];
      const half8 bh1 = Hb[(size_t)jb * 8 + 4 + quad];
      const half8 bl0 = Lb[(size_t)jb * 8 + quad];
      const half8 bl1 = Lb[(size_t)jb * 8 + 4 + quad];
      f32x4 a = {0.0f, 0.0f, 0.0f, 0.0f};
      a = __builtin_amdgcn_mfma_f32_16x16x32_f16(al0, bh0, a, 0, 0, 0);
      a = __builtin_amdgcn_mfma_f32_16x16x32_f16(al1, bh1, a, 0, 0, 0);
      a = __builtin_amdgcn_mfma_f32_16x16x32_f16(ah0, bl0, a, 0, 0, 0);
      a = __builtin_amdgcn_mfma_f32_16x16x32_f16(ah1, bl1, a, 0, 0, 0);
      a = __builtin_amdgcn_mfma_f32_16x16x32_f16(ah0, bh0, a, 0, 0, 0);
      a = __builtin_amdgcn_mfma_f32_16x16x32_f16(ah1, bh1, a, 0, 0, 0);
      acc[nj] = a;
    }
    // C layout: row = quad*4+r, col = nj*16+l15 -> dist[row][col], stride 66
#pragma unroll
    for (int nj = 0; nj < 4; ++nj)
#pragma unroll
      for (int r = 0; r < 4; ++r)
        D[(w * 16 + quad * 4 + r) * 66 + nj * 16 + l15] = acc[nj][r];
#pragma unroll
    for (int s = 0; s < 16; ++s) {
      const float dd = fmaf(-2.0f, D[(w * 16 + s) * 66 + lane], sqj);
      const unsigned long long key =
          ((unsigned long long)fmono(dd) << 32) | (unsigned int)(j0 + lane);
      sel_tile<KD_OFF>(key, w, s, lane);
    }
  }
#pragma unroll 1
  for (int s = 0; s < 16; ++s) {
    const unsigned long long m = compact_row<KD_OFF>(w, s, lane, false);
    const int i = i0 + w * 16 + s;
    if (lane < 20)
      idxout[((size_t)(b * NPT + i)) * KNB + lane] = (int)(unsigned int)m;
  }
}

// ---- EdgeConv: conv1x1 + BN + LeakyReLU + max over k neighbors ----
template <int DIN, int DS, int COUT>
__global__ __launch_bounds__(256) void edge_kernel(
    const float* __restrict__ x, const int* __restrict__ idx,
    const float* __restrict__ W, const float* __restrict__ g,
    const float* __restrict__ bia, float* __restrict__ out) {
  constexpr int CG = COUT / 64;
  const int lane = threadIdx.x & 63;
  const int wglob = blockIdx.x * 4 + (threadIdx.x >> 6);
  const int n_lin = __builtin_amdgcn_readfirstlane(wglob / CG);  // b*N+n
  const int cg = __builtin_amdgcn_readfirstlane(wglob % CG);
  const int b = n_lin >> 12;
  const int n = n_lin & (NPT - 1);
  const int c = cg * 64 + lane;

  const float* wrow = W + (size_t)c * (2 * DIN);
  const float invs = 1.0f / sqrtf(1.0f + 1e-5f);
  const float s = g[c] * invs;
  const float bias = bia[c];

  const float* xb = x + (size_t)b * (NPT * DS);
  const float* xi = xb + (size_t)n * DS;

  float wa[DIN];
  float base = 0.0f;
  if constexpr (DIN == 3) {
    wa[0] = wrow[0]; wa[1] = wrow[1]; wa[2] = wrow[2];
    const float wb0 = wrow[3], wb1 = wrow[4], wb2 = wrow[5];
    const float4 vi = *(const float4*)xi;
    base = (wb0 - wa[0]) * vi.x + (wb1 - wa[1]) * vi.y + (wb2 - wa[2]) * vi.z;
  } else {
#pragma unroll
    for (int d0 = 0; d0 < DIN; d0 += 4) {
      const float4 w4 = *(const float4*)(wrow + d0);
      wa[d0 + 0] = w4.x; wa[d0 + 1] = w4.y; wa[d0 + 2] = w4.z; wa[d0 + 3] = w4.w;
    }
#pragma unroll
    for (int d0 = 0; d0 < DIN; d0 += 4) {
      const float4 wb4 = *(const float4*)(wrow + DIN + d0);
      const float4 v0 = *(const float4*)(xi + d0);
      base += (wb4.x - wa[d0 + 0]) * v0.x + (wb4.y - wa[d0 + 1]) * v0.y +
              (wb4.z - wa[d0 + 2]) * v0.z + (wb4.w - wa[d0 + 3]) * v0.w;
    }
  }
  base = s * base + bias;

  const int* ip = idx + (size_t)n_lin * KNB;
  float m = -3.0e38f;
  for (int k = 0; k < KNB; ++k) {
    const int j = __builtin_amdgcn_readfirstlane(ip[k]);
    const float* xj = xb + (size_t)j * DS;
    float acc = 0.0f;
    if constexpr (DIN == 3) {
      const float4 v = *(const float4*)xj;
      acc = wa[0] * v.x + wa[1] * v.y + wa[2] * v.z;
    } else {
#pragma unroll
      for (int d0 = 0; d0 < DIN; d0 += 8) {
        const float4 v0 = *(const float4*)(xj + d0);
        const float4 v1 = *(const float4*)(xj + d0 + 4);
        acc += wa[d0 + 0] * v0.x + wa[d0 + 1] * v0.y + wa[d0 + 2] * v0.z +
               wa[d0 + 3] * v0.w + wa[d0 + 4] * v1.x + wa[d0 + 5] * v1.y +
               wa[d0 + 6] * v1.z + wa[d0 + 7] * v1.w;
      }
    }
    float v = s * acc + base;
    v = v > 0.0f ? v : 0.2f * v;
    m = fmaxf(m, v);
  }
  out[(size_t)n_lin * COUT + c] = m;
}

// ---- conv5 (320->1024) + BN + lrelu, fused partial max/sum pooling ----
__global__ __launch_bounds__(256) void conv5_kernel(
    const float* __restrict__ x1, const float* __restrict__ x2,
    const float* __restrict__ x3, const float* __restrict__ x4,
    const float* __restrict__ W5, const float* __restrict__ g5,
    const float* __restrict__ b5, float* __restrict__ pmax,
    float* __restrict__ psum) {
  __shared__ float xcT[320][32];
  __shared__ float wT[8][256];
  const int nb = blockIdx.x, cb = blockIdx.y, b = blockIdx.z;
  const int tid = threadIdx.x;
  const int n0 = nb * 32;

#pragma unroll
  for (int p = 0; p < 10; ++p) {
    const int q = tid + p * 256;  // [0,2560) float4s
    const int nloc = q / 80;
    const int kg = (q % 80) * 4;
    const float* src;
    int koff;
    if (kg < 64)       { src = x1 + ((size_t)(b * NPT + n0 + nloc)) * 64;  koff = kg; }
    else if (kg < 128) { src = x2 + ((size_t)(b * NPT + n0 + nloc)) * 64;  koff = kg - 64; }
    else if (kg < 192) { src = x3 + ((size_t)(b * NPT + n0 + nloc)) * 64;  koff = kg - 128; }
    else               { src = x4 + ((size_t)(b * NPT + n0 + nloc)) * 128; koff = kg - 192; }
    const float4 v = *(const float4*)(src + koff);
    xcT[kg + 0][nloc] = v.x; xcT[kg + 1][nloc] = v.y;
    xcT[kg + 2][nloc] = v.z; xcT[kg + 3][nloc] = v.w;
  }

  const int cg = tid >> 2, ng = tid & 3;
  const int c0 = cg * 4, n0t = ng * 8;
  float acc[4][8];
#pragma unroll
  for (int r = 0; r < 4; ++r)
#pragma unroll
    for (int e = 0; e < 8; ++e) acc[r][e] = 0.0f;

  for (int kt = 0; kt < 40; ++kt) {
    __syncthreads();
    {
      const float* wsrc = W5 + (size_t)(cb * 256 + tid) * 320 + kt * 8;
      const float4 a = *(const float4*)wsrc;
      const float4 b4 = *(const float4*)(wsrc + 4);
      wT[0][tid] = a.x; wT[1][tid] = a.y; wT[2][tid] = a.z; wT[3][tid] = a.w;
      wT[4][tid] = b4.x; wT[5][tid] = b4.y; wT[6][tid] = b4.z; wT[7][tid] = b4.w;
    }
    __syncthreads();
#pragma unroll
    for (int kk = 0; kk < 8; ++kk) {
      const float4 w4 = *(const float4*)&wT[kk][c0];
      const float4 xa = *(const float4*)&xcT[kt * 8 + kk][n0t];
      const float4 xb4 = *(const float4*)&xcT[kt * 8 + kk][n0t + 4];
      const float wr[4] = {w4.x, w4.y, w4.z, w4.w};
      const float xr[8] = {xa.x, xa.y, xa.z, xa.w, xb4.x, xb4.y, xb4.z, xb4.w};
#pragma unroll
      for (int r = 0; r < 4; ++r)
#pragma unroll
        for (int e = 0; e < 8; ++e) acc[r][e] = fmaf(wr[r], xr[e], acc[r][e]);
    }
  }

  const float invs = 1.0f / sqrtf(1.0f + 1e-5f);
#pragma unroll
  for (int r = 0; r < 4; ++r) {
    const int cglob = cb * 256 + c0 + r;
    const float s = g5[cglob] * invs;
    const float bb = b5[cglob];
    float mx = -3.0e38f, sm = 0.0f;
#pragma unroll
    for (int e = 0; e < 8; ++e) {
      float v = fmaf(s, acc[r][e], bb);
      v = v > 0.0f ? v : 0.2f * v;
      mx = fmaxf(mx, v);
      sm += v;
    }
    mx = fmaxf(mx, __shfl_xor(mx, 1, 64));
    mx = fmaxf(mx, __shfl_xor(mx, 2, 64));
    sm += __shfl_xor(sm, 1, 64);
    sm += __shfl_xor(sm, 2, 64);
    if (ng == 0) {
      pmax[((size_t)b * 1024 + cglob) * 128 + nb] = mx;
      psum[((size_t)b * 1024 + cglob) * 128 + nb] = sm;
    }
  }
}

// ---- reduce partials -> gfeat [B][2048] = [gmax | gavg] ----
__global__ __launch_bounds__(256) void reduce5(const float* __restrict__ pmax,
                                               const float* __restrict__ psum,
                                               float* __restrict__ gfeat) {
  const int t = blockIdx.x * 256 + threadIdx.x;  // < 8192 = B*1024
  const int b = t >> 10, c = t & 1023;
  const float* pm = pmax + (size_t)t * 128;
  const float* ps = psum + (size_t)t * 128;
  float mx = -3.0e38f, sm = 0.0f;
  for (int i = 0; i < 128; i += 4) {
    const float4 v = *(const float4*)(pm + i);
    mx = fmaxf(mx, fmaxf(fmaxf(v.x, v.y), fmaxf(v.z, v.w)));
    const float4 u = *(const float4*)(ps + i);
    sm += (u.x + u.y) + (u.z + u.w);
  }
  gfeat[b * 2048 + c] = mx;
  gfeat[b * 2048 + 1024 + c] = sm * (1.0f / 4096.0f);
}

// ---- head: y1 = lrelu(bn(gfeat @ Wl1^T)) ----
__global__ __launch_bounds__(256) void head1(const float* __restrict__ gfeat,
                                             const float* __restrict__ Wl1,
                                             const float* __restrict__ g6,
                                             const float* __restrict__ b6,
                                             float* __restrict__ y1g) {
  __shared__ float gf[2048];
  __shared__ float red[256];
  const int tid = threadIdx.x;
  const int cb = blockIdx.x, b = blockIdx.y;
  const float4* gsrc = (const float4*)(gfeat + b * 2048);
  for (int p = tid; p < 512; p += 256) ((float4*)gf)[p] = gsrc[p];
  __syncthreads();
  const int cl = cb * 64 + (tid >> 2);
  const int q = tid & 3;
  const float* wr = Wl1 + (size_t)cl * 2048 + q * 512;
  const float* gq = gf + q * 512;
  float acc = 0.0f;
  for (int k0 = 0; k0 < 512; k0 += 8) {
    const float4 w0 = *(const float4*)(wr + k0);
    const float4 w1 = *(const float4*)(wr + k0 + 4);
    acc = fmaf(w0.x, gq[k0 + 0], acc); acc = fmaf(w0.y, gq[k0 + 1], acc);
    acc = fmaf(w0.z, gq[k0 + 2], acc); acc = fmaf(w0.w, gq[k0 + 3], acc);
    acc = fmaf(w1.x, gq[k0 + 4], acc); acc = fmaf(w1.y, gq[k0 + 5], acc);
    acc = fmaf(w1.z, gq[k0 + 6], acc); acc = fmaf(w1.w, gq[k0 + 7], acc);
  }
  red[tid] = acc;
  __syncthreads();
  if (q == 0) {
    float v = red[tid] + red[tid + 1] + red[tid + 2] + red[tid + 3];
    const float invs = 1.0f / sqrtf(1.0f + 1e-5f);
    v = fmaf(g6[cl] * invs, v, b6[cl]);
    v = v > 0.0f ? v : 0.2f * v;
    y1g[b * 512 + cl] = v;
  }
}

// ---- head: y2, y3, broadcast to [B][N][5] fp32 ----
__global__ __launch_bounds__(256) void head2(
    const float* __restrict__ y1g, const float* __restrict__ Wl2,
    const float* __restrict__ bl2, const float* __restrict__ g7,
    const float* __restrict__ b7, const float* __restrict__ Wl3,
    const float* __restrict__ bl3, float* __restrict__ out) {
  __shared__ float y1s[512];
  __shared__ float y2s[256];
  __shared__ float y3s[5];
  const int b = blockIdx.x;
  const int t = threadIdx.x;
  y1s[t] = y1g[b * 512 + t];
  y1s[t + 256] = y1g[b * 512 + t + 256];
  __syncthreads();
  {
    const float* wr = Wl2 + (size_t)t * 512;
    float acc = 0.0f;
    for (int k0 = 0; k0 < 512; k0 += 8) {
      const float4 w0 = *(const float4*)(wr + k0);
      const float4 w1 = *(const float4*)(wr + k0 + 4);
      acc = fmaf(w0.x, y1s[k0 + 0], acc); acc = fmaf(w0.y, y1s[k0 + 1], acc);
      acc = fmaf(w0.z, y1s[k0 + 2], acc); acc = fmaf(w0.w, y1s[k0 + 3], acc);
      acc = fmaf(w1.x, y1s[k0 + 4], acc); acc = fmaf(w1.y, y1s[k0 + 5], acc);
      acc = fmaf(w1.z, y1s[k0 + 6], acc); acc = fmaf(w1.w, y1s[k0 + 7], acc);
    }
    const float invs = 1.0f / sqrtf(1.0f + 1e-5f);
    float v = acc + bl2[t];
    v = fmaf(g7[t] * invs, v, b7[t]);
    v = v > 0.0f ? v : 0.2f * v;
    y2s[t] = v;
  }
  __syncthreads();
  if (t < 5) {
    const float* wr = Wl3 + (size_t)t * 256;
    float acc = 0.0f;
    for (int k = 0; k < 256; ++k) acc += wr[k] * y2s[k];
    y3s[t] = acc + bl3[t];
  }
  __syncthreads();
  for (int e = t; e < NPT * 5; e += 256)
    out[(size_t)b * (NPT * 5) + e] = y3s[e % 5];
}

extern "C" void kernel_launch(void* const* d_in, const int* in_sizes, int n_in,
                              void* d_out, int out_size, void* d_ws, size_t ws_size,
                              hipStream_t stream) {
  (void)in_sizes; (void)n_in; (void)out_size;
  const float* xyz = (const float*)d_in[0];
  const float* W1  = (const float*)d_in[1];
  const float* g1  = (const float*)d_in[2];
  const float* b1  = (const float*)d_in[3];
  const float* W2  = (const float*)d_in[4];
  const float* g2  = (const float*)d_in[5];
  const float* b2  = (const float*)d_in[6];
  const float* W3  = (const float*)d_in[7];
  const float* g3  = (const float*)d_in[8];
  const float* b3  = (const float*)d_in[9];
  const float* W4  = (const float*)d_in[10];
  const float* g4  = (const float*)d_in[11];
  const float* b4  = (const float*)d_in[12];
  const float* W5  = (const float*)d_in[13];
  const float* g5  = (const float*)d_in[14];
  const float* b5  = (const float*)d_in[15];
  const float* Wl1 = (const float*)d_in[16];
  const float* g6  = (const float*)d_in[17];
  const float* b6  = (const float*)d_in[18];
  const float* Wl2 = (const float*)d_in[19];
  const float* bl2 = (const float*)d_in[20];
  const float* g7  = (const float*)d_in[21];
  const float* b7  = (const float*)d_in[22];
  const float* Wl3 = (const float*)d_in[23];
  const float* bl3 = (const float*)d_in[24];

  char* ws = (char*)d_ws;
  float* x0    = (float*)(ws + 0);         //  524288 B
  float* x1    = (float*)(ws + 524288);    // 8388608 B
  float* x2    = (float*)(ws + 8912896);   // 8388608 B
  float* x3    = (float*)(ws + 17301504);  // 8388608 B
  float* x4    = (float*)(ws + 25690112);  // 16777216 B
  float* sqb   = (float*)(ws + 42467328);  //  131072 B
  int*   idxb  = (int*)  (ws + 42598400);  // 2621440 B
  float* pmx   = (float*)(ws + 45219840);  // 4194304 B (aliased: xhi during knn)
  float* psm   = (float*)(ws + 49414144);  // 4194304 B (aliased: xlo during knn)
  float* gfeat = (float*)(ws + 53608448);  //   65536 B
  float* y1g   = (float*)(ws + 53673984);  //   16384 B
  if (ws_size < 53690368) return;          // need ~51.2 MB scratch

  unsigned short* xhi = (unsigned short*)pmx;  // 4 MB, used before conv5
  unsigned short* xlo = (unsigned short*)psm;  // 4 MB, used before conv5

  cvt_xyz<<<128, 256, 0, stream>>>(xyz, x0);

  knn3<<<dim3(64, 8), 256, 43776, stream>>>(x0, idxb);
  edge_kernel<3, 4, 64><<<8192, 256, 0, stream>>>(x0, idxb, W1, g1, b1, x1);

  sqsplit<<<512, 256, 0, stream>>>(x1, sqb, xhi, xlo);
  knn_mfma<<<dim3(64, 8), 256, 60672, stream>>>(xhi, xlo, sqb, idxb);
  edge_kernel<64, 64, 64><<<8192, 256, 0, stream>>>(x1, idxb, W2, g2, b2, x2);

  sqsplit<<<512, 256, 0, stream>>>(x2, sqb, xhi, xlo);
  knn_mfma<<<dim3(64, 8), 256, 60672, stream>>>(xhi, xlo, sqb, idxb);
  edge_kernel<64, 64, 64><<<8192, 256, 0, stream>>>(x2, idxb, W3, g3, b3, x3);

  sqsplit<<<512, 256, 0, stream>>>(x3, sqb, xhi, xlo);
  knn_mfma<<<dim3(64, 8), 256, 60672, stream>>>(xhi, xlo, sqb, idxb);
  edge_kernel<64, 64, 128><<<16384, 256, 0, stream>>>(x3, idxb, W4, g4, b4, x4);

  conv5_kernel<<<dim3(128, 4, 8), 256, 0, stream>>>(x1, x2, x3, x4, W5, g5, b5, pmx, psm);
  reduce5<<<32, 256, 0, stream>>>(pmx, psm, gfeat);
  head1<<<dim3(8, 8), 256, 0, stream>>>(gfeat, Wl1, g6, b6, y1g);
  head2<<<8, 256, 0, stream>>>(y1g, Wl2, bl2, g7, b7, Wl3, bl3, (float*)d_out);
}